// Round 10
// baseline (124.688 us; speedup 1.0000x reference)
//
#include <hip/hip_runtime.h>
#include <hip/hip_fp16.h>
#include <cstdint>
#include <cstddef>

// BasicViTNCA3D: 24^3 cells, C=128, 8 heads x dim16, MLP 512, 2 NCA steps.
// R10 = R9 + attention op-count restructure:
//  - neighbor-slice split: 4 thr/(cell,head) each do FULL 16-ch dot for 7 of 28
//    (padded) neighbors -> per-neighbor shfls (54/thr) -> one final butterfly (24);
//    serial den chain 27 -> 7.
//  - per-block LDS neighbor table {byte_off, den_w, pv_w} kills clamp/addr ALU.
//  - SCALE folded into q (exact pow2); v_rcp for 1/den.
#define NCELL 13824

typedef short bf16x8 __attribute__((ext_vector_type(8)));  // 8 bf16 (4 VGPRs)
typedef float f32x4  __attribute__((ext_vector_type(4)));  // MFMA acc
typedef _Float16 h2v __attribute__((ext_vector_type(2)));

__device__ __forceinline__ unsigned short f2bf(float x) {
  union { float f; uint32_t u; } c; c.f = x;
  uint32_t r = c.u + 0x7fffu + ((c.u >> 16) & 1u);  // RNE
  return (unsigned short)(r >> 16);
}

// A-fragment (16x32 tile, row = lane&15, k = (lane>>4)*8+j) from fp32 LDS row
__device__ __forceinline__ bf16x8 afrag_f32(const float* p) {
  float4 u0 = *(const float4*)p;
  float4 u1 = *(const float4*)(p + 4);
  bf16x8 a;
  a[0] = (short)f2bf(u0.x); a[1] = (short)f2bf(u0.y);
  a[2] = (short)f2bf(u0.z); a[3] = (short)f2bf(u0.w);
  a[4] = (short)f2bf(u1.x); a[5] = (short)f2bf(u1.y);
  a[6] = (short)f2bf(u1.z); a[7] = (short)f2bf(u1.w);
  return a;
}

// f32 += dot(half2, half2) via v_dot2_f32_f16 when available
__device__ __forceinline__ float fdot2(__half2 a, __half2 b, float c) {
#if __has_builtin(__builtin_amdgcn_fdot2)
  union { __half2 h; h2v n; } ua, ub;
  ua.h = a; ub.h = b;
  return __builtin_amdgcn_fdot2(ua.n, ub.n, c, false);
#else
  __half2 d = __hmul2(a, b);
  return c + __low2float(d) + __high2float(d);
#endif
}

__device__ __forceinline__ __half2 shflx(__half2 v, int m) {
  union { __half2 h; int i; } c; c.h = v;
  c.i = __shfl_xor(c.i, m);
  return c.h;
}

// inf-safe tanh-form GELU (max abs dev ~1e-3 vs exact erf GELU)
__device__ __forceinline__ float gelu_f(float x) {
  float u = 0.7978845608f * x * (1.f + 0.044715f * x * x);
  float e = __expf(2.f * u);
  float t = 1.f - 2.f / (e + 1.f);   // tanh(u)
  return 0.5f * x * (1.f + t);
}

// ---------------- Threefry-2x32 (JAX-compatible) ----------------
__device__ __forceinline__ void tf2x32(uint32_t k0, uint32_t k1,
                                       uint32_t x0, uint32_t x1,
                                       uint32_t& o0, uint32_t& o1) {
  uint32_t k2 = k0 ^ k1 ^ 0x1BD11BDAu;
  x0 += k0; x1 += k1;
#define TFR(r) { x0 += x1; x1 = (x1 << (r)) | (x1 >> (32 - (r))); x1 ^= x0; }
  TFR(13) TFR(15) TFR(26) TFR(6)   x0 += k1; x1 += k2 + 1u;
  TFR(17) TFR(29) TFR(16) TFR(24)  x0 += k2; x1 += k0 + 2u;
  TFR(13) TFR(15) TFR(26) TFR(6)   x0 += k0; x1 += k1 + 3u;
  TFR(17) TFR(29) TFR(16) TFR(24)  x0 += k1; x1 += k2 + 4u;
  TFR(13) TFR(15) TFR(26) TFR(6)   x0 += k2; x1 += k0 + 5u;
#undef TFR
  o0 = x0; o1 = x1;
}

__device__ __forceinline__ float pe_val(int n, int c) {
  int dd = n % 24, ww = (n / 24) % 24, hh = n / 576;
  if (c == 126)
    return sinf((float)hh) + sinf(0.01f * (float)ww) + sinf(0.0001f * (float)dd);
  return cosf((float)hh) + cosf(0.01f * (float)ww) + cosf(0.0001f * (float)dd);
}

// ---------------- packAll: 5 weights -> MFMA B-frag bf16 ----------------
__device__ __forceinline__ void packOne(const float* __restrict__ W, int K, int N,
                                        unsigned short* __restrict__ P, int f) {
  int KT = K >> 5;
  int lane = f & 63;
  int ft = f >> 6;
  int kt = ft % KT, nt = ft / KT;
  int col = nt * 16 + (lane & 15);
  int k0 = kt * 32 + (lane >> 4) * 8;
  uint32_t w[4];
  #pragma unroll
  for (int p = 0; p < 4; ++p) {
    uint32_t lo = f2bf(W[(size_t)(k0 + 2 * p) * N + col]);
    uint32_t hi = f2bf(W[(size_t)(k0 + 2 * p + 1) * N + col]);
    w[p] = lo | (hi << 16);
  }
  uint4 v; v.x = w[0]; v.y = w[1]; v.z = w[2]; v.w = w[3];
  ((uint4*)P)[f] = v;
}

__global__ __launch_bounds__(256) void packAll(
    const float* __restrict__ Wqkv, const float* __restrict__ Wout,
    const float* __restrict__ Wff1, const float* __restrict__ Wff2,
    const float* __restrict__ Whead,
    unsigned short* __restrict__ pQkv, unsigned short* __restrict__ pOut,
    unsigned short* __restrict__ pFF1, unsigned short* __restrict__ pFF2,
    unsigned short* __restrict__ pHead) {
  int f = blockIdx.x * 256 + threadIdx.x;
  if (f < 6144)        packOne(Wqkv, 128, 384, pQkv, f);
  else if (f < 8192)   packOne(Wout, 128, 128, pOut, f - 6144);
  else if (f < 16384)  packOne(Wff1, 128, 512, pFF1, f - 8192);
  else if (f < 24576)  packOne(Wff2, 512, 128, pFF2, f - 16384);
  else if (f < 26624)  packOne(Whead, 128, 128, pHead, f - 24576);
}

// ---------------- K1: pe + LN1 + qkv GEMM (step 0 only) ----------------
__global__ __launch_bounds__(256) void nca_k1(
    const float* __restrict__ x, const float* __restrict__ ln1s,
    const float* __restrict__ ln1b, const unsigned short* __restrict__ pQkv,
    __half* __restrict__ wqkv,
    const int* __restrict__ steps, int s) {
  if (s >= *steps) return;
  __shared__ float ly[16][132];
  __shared__ float lmean[16], lrstd[16];
  const int t = threadIdx.x;
  const int swz = (blockIdx.x & 7) * 108 + (blockIdx.x >> 3);  // XCD-contiguous
  const int base = swz * 16;
  #pragma unroll
  for (int i = 0; i < 8; ++i) {
    int idx = i * 256 + t;
    int r = idx >> 7, c = idx & 127;
    int n = base + r;
    ly[r][c] = (c < 126) ? x[(size_t)n * 128 + c] : pe_val(n, c);
  }
  __syncthreads();
  { int r = t >> 4, j = t & 15;
    float s1 = 0.f, s2 = 0.f;
    #pragma unroll
    for (int cc = 0; cc < 8; ++cc) { float v = ly[r][j * 8 + cc]; s1 += v; s2 += v * v; }
    #pragma unroll
    for (int off = 1; off < 16; off <<= 1) { s1 += __shfl_xor(s1, off); s2 += __shfl_xor(s2, off); }
    if (j == 0) {
      float m = s1 * (1.f / 128.f);
      float var = s2 * (1.f / 128.f) - m * m;
      lmean[r] = m; lrstd[r] = rsqrtf(var + 1e-5f);
    }
  }
  __syncthreads();
  #pragma unroll
  for (int i = 0; i < 8; ++i) {
    int idx = i * 256 + t;
    int r = idx >> 7, c = idx & 127;
    ly[r][c] = (ly[r][c] - lmean[r]) * lrstd[r] * ln1s[c] + ln1b[c];
  }
  __syncthreads();
  const int w = t >> 6, l = t & 63;
  bf16x8 a4[4];
  #pragma unroll
  for (int kt = 0; kt < 4; ++kt)
    a4[kt] = afrag_f32(&ly[l & 15][kt * 32 + (l >> 4) * 8]);
  const bf16x8* B = (const bf16x8*)pQkv;
  #pragma unroll
  for (int q = 0; q < 6; ++q) {
    f32x4 acc = (f32x4){0.f, 0.f, 0.f, 0.f};
    int nt = w * 6 + q;
    #pragma unroll
    for (int kt = 0; kt < 4; ++kt)
      acc = __builtin_amdgcn_mfma_f32_16x16x32_bf16(a4[kt], B[(nt * 4 + kt) * 64 + l], acc, 0, 0, 0);
    int col = nt * 16 + (l & 15);
    #pragma unroll
    for (int j = 0; j < 4; ++j)
      wqkv[(size_t)(base + (l >> 4) * 4 + j) * 384 + col] = __float2half(acc[j]);
  }
}

// ---- kA: attn + out-proj + LN2 + FF1 + FF2 + LN3 + head + mask-update + next qkv ----
__global__ __launch_bounds__(512, 4) void nca_kA(
    const __half* __restrict__ qkv, __half* __restrict__ qkvN,
    const unsigned short* __restrict__ pQkv,
    const unsigned short* __restrict__ pOut, const float* __restrict__ bout,
    const float* __restrict__ ln1s, const float* __restrict__ ln1b,
    const float* __restrict__ ln2s, const float* __restrict__ ln2b,
    const unsigned short* __restrict__ pFF1, const float* __restrict__ bff1,
    const unsigned short* __restrict__ pFF2, const float* __restrict__ bff2,
    const float* __restrict__ ln3s, const float* __restrict__ ln3b,
    const unsigned short* __restrict__ pHead, const float* __restrict__ bhead,
    const float* __restrict__ xin, float* __restrict__ xout,
    const int* __restrict__ steps, int s) {
  if (s >= *steps) return;
  __shared__ unsigned short lnorm[16][136];  // bf16: attn-out / ln2 / ln3 / ln1'
  __shared__ float ly2[16][132];             // f32: y2 -> y3 (in place) -> x_new
  __shared__ unsigned short lh[16][520];     // bf16: GELU(FF1)
  __shared__ float4 ltab[16][28];            // {byte_off, den_w, pv_w, 0} per neighbor
  __shared__ float lmask[16];
  const int t = threadIdx.x;
  const int swz = (blockIdx.x & 7) * 108 + (blockIdx.x >> 3);  // XCD-contiguous
  const int base = swz * 16;
  const int w = t >> 6, l = t & 63;
  const int lr = (l >> 4) * 4, lc = l & 15;

  // prefetch residual x for this thread's GEMM output slots (consumed post-barrier)
  float xres[4];
  {
    int col = w * 16 + lc;
    #pragma unroll
    for (int j = 0; j < 4; ++j)
      xres[j] = xin[(size_t)(base + lr + j) * 128 + col];
  }
  if (t < 16) { // JAX threefry per-cell mask (partitionable random_bits)
    uint32_t kk0, kk1, b0, b1;
    tf2x32(0u, 42u, 0u, (uint32_t)s, kk0, kk1);
    tf2x32(kk0, kk1, 0u, (uint32_t)(base + t), b0, b1);
    uint32_t bits = b0 ^ b1;
    lmask[t] = ((bits >> 9) > 0x400000u) ? 1.0f : 0.0f;
  }
  // ---- neighbor table: 16 cells x 28 entries (entry 27 = masked pad) ----
  if ((t & 31) < 28) {
    int cell = t >> 5, j = t & 31;
    int n = base + cell;
    int dd = n % 24, ww = (n / 24) % 24, hh = n / 576;
    bool real = j < 27;
    int jj = real ? j : 13;                    // pad -> center, weights 0
    int di = jj / 9 - 1, dj2 = (jj / 3) % 3 - 1, dk = jj % 3 - 1;
    int h2 = hh + di, w2 = ww + dj2, d2 = dd + dk;
    bool ok = ((unsigned)h2 < 24u) && ((unsigned)w2 < 24u) && ((unsigned)d2 < 24u);
    int nn = min(max(h2, 0), 23) * 576 + min(max(w2, 0), 23) * 24 + min(max(d2, 0), 23);
    float4 e4;
    e4.x = __int_as_float(nn * 768);           // byte offset of qkv row
    e4.y = real ? 1.f : 0.f;                   // den weight (OOB: e==1 counted)
    e4.z = (real && ok) ? 1.f : 0.f;           // dot & PV weight
    e4.w = 0.f;
    ltab[cell][j] = e4;
  }
  __syncthreads();
  // ---- attention: 4 thr/(cell,head), each full 16-ch dot for 7 neighbors ----
  {
    const int cell = t >> 5, head = (t >> 2) & 7, qr = t & 3;
    const int n = base + cell;
    const __half2* qp = (const __half2*)(qkv + (size_t)n * 384 + head * 16);
    const __half2 qs = __float2half2_rn(0.25f);    // SCALE folded (exact pow2)
    __half2 q0 = __hmul2(qp[0], qs), q1 = __hmul2(qp[1], qs),
            q2 = __hmul2(qp[2], qs), q3 = __hmul2(qp[3], qs),
            q4 = __hmul2(qp[4], qs), q5 = __hmul2(qp[5], qs),
            q6 = __hmul2(qp[6], qs), q7 = __hmul2(qp[7], qs);
    const char* kvb = (const char*)qkv + 256 + head * 32;  // K section + head
    const float4* tp = &ltab[cell][qr * 7];
    const __half2 hz = __float2half2_rn(0.f);
    float den = 0.f;
    __half2 av0=hz,av1=hz,av2=hz,av3=hz,av4=hz,av5=hz,av6=hz,av7=hz;
    #pragma unroll
    for (int i = 0; i < 7; ++i) {
      float4 e4 = tp[i];
      const char* p = kvb + __float_as_int(e4.x);
      uint4 ka = *(const uint4*)p;                  // K ch0-7
      uint4 kb2 = *(const uint4*)(p + 16);          // K ch8-15
      uint4 va = *(const uint4*)(p + 256);          // V ch0-7
      uint4 vb = *(const uint4*)(p + 272);          // V ch8-15
      union { uint32_t u; __half2 h; } c;
      float dotc = 0.f;
      c.u = ka.x;  dotc = fdot2(q0, c.h, dotc);
      c.u = ka.y;  dotc = fdot2(q1, c.h, dotc);
      c.u = ka.z;  dotc = fdot2(q2, c.h, dotc);
      c.u = ka.w;  dotc = fdot2(q3, c.h, dotc);
      c.u = kb2.x; dotc = fdot2(q4, c.h, dotc);
      c.u = kb2.y; dotc = fdot2(q5, c.h, dotc);
      c.u = kb2.z; dotc = fdot2(q6, c.h, dotc);
      c.u = kb2.w; dotc = fdot2(q7, c.h, dotc);
      float e = __expf(dotc * e4.z);                // OOB/pad -> exp(0)=1
      den = fmaf(e, e4.y, den);                     // pad adds 0, OOB adds 1
      __half2 ew = __float2half2_rn(e * e4.z);      // OOB/pad: PV weight 0
      c.u = va.x; av0 = __hfma2(ew, c.h, av0);
      c.u = va.y; av1 = __hfma2(ew, c.h, av1);
      c.u = va.z; av2 = __hfma2(ew, c.h, av2);
      c.u = va.w; av3 = __hfma2(ew, c.h, av3);
      c.u = vb.x; av4 = __hfma2(ew, c.h, av4);
      c.u = vb.y; av5 = __hfma2(ew, c.h, av5);
      c.u = vb.z; av6 = __hfma2(ew, c.h, av6);
      c.u = vb.w; av7 = __hfma2(ew, c.h, av7);
    }
    // combine the 4 slice-threads (lanes qr=0..3 within each 4-lane group)
    den += __shfl_xor(den, 1); den += __shfl_xor(den, 2);
#define CMB(v) { v = __hadd2(v, shflx(v, 1)); v = __hadd2(v, shflx(v, 2)); }
    CMB(av0) CMB(av1) CMB(av2) CMB(av3) CMB(av4) CMB(av5) CMB(av6) CMB(av7)
#undef CMB
    float inv = __builtin_amdgcn_rcpf(den);
    __half2 r0 = (qr == 0) ? av0 : (qr == 1) ? av2 : (qr == 2) ? av4 : av6;
    __half2 r1 = (qr == 0) ? av1 : (qr == 1) ? av3 : (qr == 2) ? av5 : av7;
    float2 f0 = __half22float2(r0), f1 = __half22float2(r1);
    uint32_t w0 = (uint32_t)f2bf(f0.x * inv) | ((uint32_t)f2bf(f0.y * inv) << 16);
    uint32_t w1 = (uint32_t)f2bf(f1.x * inv) | ((uint32_t)f2bf(f1.y * inv) << 16);
    *(uint2*)&lnorm[cell][head * 16 + qr * 4] = (uint2){w0, w1};
  }
  __syncthreads();
  // ---- out-proj: wave w -> coltile w; epilogue y2 -> ly2 (f32) ----
  bf16x8 a4[4];
  #pragma unroll
  for (int kt = 0; kt < 4; ++kt)
    a4[kt] = *(const bf16x8*)&lnorm[l & 15][kt * 32 + (l >> 4) * 8];
  {
    f32x4 acc = (f32x4){0.f,0.f,0.f,0.f};
    const bf16x8* B = (const bf16x8*)pOut;
    #pragma unroll
    for (int kt = 0; kt < 4; ++kt)
      acc = __builtin_amdgcn_mfma_f32_16x16x32_bf16(a4[kt], B[(w * 4 + kt) * 64 + l], acc, 0, 0, 0);
    int col = w * 16 + lc;
    #pragma unroll
    for (int j = 0; j < 4; ++j) {
      int r = lr + j, n = base + r;
      float resy = (col < 126) ? xres[j] : pe_val(n, col);  // y residual has pe
      ly2[r][col] = acc[j] + bout[col] + resy;
    }
  }
  __syncthreads();
  { // ---- LN2: butterfly stats + normalize own 4 ch -> lnorm bf16 ----
    int r = t >> 5, j = t & 31;
    float v0 = ly2[r][j*4], v1 = ly2[r][j*4+1], v2 = ly2[r][j*4+2], v3 = ly2[r][j*4+3];
    float s1 = v0 + v1 + v2 + v3;
    float s2 = v0*v0 + v1*v1 + v2*v2 + v3*v3;
    #pragma unroll
    for (int off = 1; off < 32; off <<= 1) { s1 += __shfl_xor(s1, off); s2 += __shfl_xor(s2, off); }
    float m = s1 * (1.f / 128.f);
    float rstd = rsqrtf(s2 * (1.f / 128.f) - m * m + 1e-5f);
    float n0 = (v0 - m) * rstd * ln2s[j*4]   + ln2b[j*4];
    float n1 = (v1 - m) * rstd * ln2s[j*4+1] + ln2b[j*4+1];
    float n2 = (v2 - m) * rstd * ln2s[j*4+2] + ln2b[j*4+2];
    float n3 = (v3 - m) * rstd * ln2s[j*4+3] + ln2b[j*4+3];
    uint32_t w0 = (uint32_t)f2bf(n0) | ((uint32_t)f2bf(n1) << 16);
    uint32_t w1 = (uint32_t)f2bf(n2) | ((uint32_t)f2bf(n3) << 16);
    *(uint2*)&lnorm[r][j * 4] = (uint2){w0, w1};
  }
  __syncthreads();
  // ---- FF1: wave w -> coltiles w*4..w*4+3; fast GELU -> lh bf16 ----
  #pragma unroll
  for (int kt = 0; kt < 4; ++kt)
    a4[kt] = *(const bf16x8*)&lnorm[l & 15][kt * 32 + (l >> 4) * 8];
  {
    f32x4 acc[4];
    #pragma unroll
    for (int q = 0; q < 4; ++q) acc[q] = (f32x4){0.f,0.f,0.f,0.f};
    const bf16x8* B = (const bf16x8*)pFF1;
    #pragma unroll
    for (int kt = 0; kt < 4; ++kt) {
      #pragma unroll
      for (int q = 0; q < 4; ++q) {
        int nt = w * 4 + q;
        acc[q] = __builtin_amdgcn_mfma_f32_16x16x32_bf16(a4[kt], B[(nt * 4 + kt) * 64 + l], acc[q], 0, 0, 0);
      }
    }
    #pragma unroll
    for (int q = 0; q < 4; ++q) {
      int col = (w * 4 + q) * 16 + lc;
      #pragma unroll
      for (int j = 0; j < 4; ++j)
        lh[lr + j][col] = f2bf(gelu_f(acc[q][j] + bff1[col]));
    }
  }
  __syncthreads();
  // ---- FF2: K=512, wave w -> coltile w; y3 = acc + b + y2 in place (owner) ----
  {
    f32x4 acc = (f32x4){0.f,0.f,0.f,0.f};
    const bf16x8* B = (const bf16x8*)pFF2;
    #pragma unroll
    for (int kt = 0; kt < 16; ++kt) {
      bf16x8 a = *(const bf16x8*)&lh[l & 15][kt * 32 + (l >> 4) * 8];
      acc = __builtin_amdgcn_mfma_f32_16x16x32_bf16(a, B[(w * 16 + kt) * 64 + l], acc, 0, 0, 0);
    }
    int col = w * 16 + lc;
    #pragma unroll
    for (int j = 0; j < 4; ++j) {
      int r = lr + j;
      ly2[r][col] = acc[j] + bff2[col] + ly2[r][col];
    }
  }
  __syncthreads();
  { // ---- LN3: butterfly stats + normalize -> lnorm bf16 ----
    int r = t >> 5, j = t & 31;
    float v0 = ly2[r][j*4], v1 = ly2[r][j*4+1], v2 = ly2[r][j*4+2], v3 = ly2[r][j*4+3];
    float s1 = v0 + v1 + v2 + v3;
    float s2 = v0*v0 + v1*v1 + v2*v2 + v3*v3;
    #pragma unroll
    for (int off = 1; off < 32; off <<= 1) { s1 += __shfl_xor(s1, off); s2 += __shfl_xor(s2, off); }
    float m = s1 * (1.f / 128.f);
    float rstd = rsqrtf(s2 * (1.f / 128.f) - m * m + 1e-5f);
    float n0 = (v0 - m) * rstd * ln3s[j*4]   + ln3b[j*4];
    float n1 = (v1 - m) * rstd * ln3s[j*4+1] + ln3b[j*4+1];
    float n2 = (v2 - m) * rstd * ln3s[j*4+2] + ln3b[j*4+2];
    float n3 = (v3 - m) * rstd * ln3s[j*4+3] + ln3b[j*4+3];
    uint32_t w0 = (uint32_t)f2bf(n0) | ((uint32_t)f2bf(n1) << 16);
    uint32_t w1 = (uint32_t)f2bf(n2) | ((uint32_t)f2bf(n3) << 16);
    *(uint2*)&lnorm[r][j * 4] = (uint2){w0, w1};
  }
  __syncthreads();
  // ---- head: wave w -> coltile w; dx; masked update; x_new -> ly2 ----
  #pragma unroll
  for (int kt = 0; kt < 4; ++kt)
    a4[kt] = *(const bf16x8*)&lnorm[l & 15][kt * 32 + (l >> 4) * 8];
  {
    f32x4 acc = (f32x4){0.f,0.f,0.f,0.f};
    const bf16x8* B = (const bf16x8*)pHead;
    #pragma unroll
    for (int kt = 0; kt < 4; ++kt)
      acc = __builtin_amdgcn_mfma_f32_16x16x32_bf16(a4[kt], B[(w * 4 + kt) * 64 + l], acc, 0, 0, 0);
    int col = w * 16 + lc;
    #pragma unroll
    for (int j = 0; j < 4; ++j) {
      int r = lr + j;
      size_t n = base + r;
      float dx = acc[j] + bhead[col];
      float xn = xres[j] + dx * lmask[r];
      xout[n * 128 + col] = xn;
      ly2[r][col] = xn;
    }
  }
  // ---- tail: next step's pe + LN1 + qkv GEMM (skipped on last step) ----
  if (s + 1 < *steps) {
    __syncthreads();
    if (t < 32) { int r = t >> 1, c = 126 + (t & 1); ly2[r][c] = pe_val(base + r, c); }
    __syncthreads();
    { // LN1: butterfly stats + normalize -> lnorm bf16
      int r = t >> 5, j = t & 31;
      float v0 = ly2[r][j*4], v1 = ly2[r][j*4+1], v2 = ly2[r][j*4+2], v3 = ly2[r][j*4+3];
      float s1 = v0 + v1 + v2 + v3;
      float s2 = v0*v0 + v1*v1 + v2*v2 + v3*v3;
      #pragma unroll
      for (int off = 1; off < 32; off <<= 1) { s1 += __shfl_xor(s1, off); s2 += __shfl_xor(s2, off); }
      float m = s1 * (1.f / 128.f);
      float rstd = rsqrtf(s2 * (1.f / 128.f) - m * m + 1e-5f);
      float n0 = (v0 - m) * rstd * ln1s[j*4]   + ln1b[j*4];
      float n1 = (v1 - m) * rstd * ln1s[j*4+1] + ln1b[j*4+1];
      float n2 = (v2 - m) * rstd * ln1s[j*4+2] + ln1b[j*4+2];
      float n3 = (v3 - m) * rstd * ln1s[j*4+3] + ln1b[j*4+3];
      uint32_t w0 = (uint32_t)f2bf(n0) | ((uint32_t)f2bf(n1) << 16);
      uint32_t w1 = (uint32_t)f2bf(n2) | ((uint32_t)f2bf(n3) << 16);
      *(uint2*)&lnorm[r][j * 4] = (uint2){w0, w1};
    }
    __syncthreads();
    #pragma unroll
    for (int kt = 0; kt < 4; ++kt)
      a4[kt] = *(const bf16x8*)&lnorm[l & 15][kt * 32 + (l >> 4) * 8];
    const bf16x8* B = (const bf16x8*)pQkv;
    #pragma unroll
    for (int q = 0; q < 3; ++q) {
      f32x4 acc = (f32x4){0.f,0.f,0.f,0.f};
      int nt = w * 3 + q;
      #pragma unroll
      for (int kt = 0; kt < 4; ++kt)
        acc = __builtin_amdgcn_mfma_f32_16x16x32_bf16(a4[kt], B[(nt * 4 + kt) * 64 + l], acc, 0, 0, 0);
      int col = nt * 16 + lc;
      #pragma unroll
      for (int j = 0; j < 4; ++j)
        qkvN[(size_t)(base + lr + j) * 384 + col] = __float2half(acc[j]);
    }
  }
}

extern "C" void kernel_launch(void* const* d_in, const int* in_sizes, int n_in,
                              void* d_out, int out_size, void* d_ws, size_t ws_size,
                              hipStream_t stream) {
  const float* x0   = (const float*)d_in[0];
  const float* Wqkv = (const float*)d_in[1];
  const float* Wout = (const float*)d_in[2];
  const float* bout = (const float*)d_in[3];
  const float* ln1s = (const float*)d_in[4];
  const float* ln1b = (const float*)d_in[5];
  const float* Wff1 = (const float*)d_in[6];
  const float* bff1 = (const float*)d_in[7];
  const float* Wff2 = (const float*)d_in[8];
  const float* bff2 = (const float*)d_in[9];
  const float* ln2s = (const float*)d_in[10];
  const float* ln2b = (const float*)d_in[11];
  const float* ln3s = (const float*)d_in[12];
  const float* ln3b = (const float*)d_in[13];
  const float* Whead= (const float*)d_in[14];
  const float* bhead= (const float*)d_in[15];
  const int*   steps= (const int*)d_in[16];
  float* out = (float*)d_out;

  __half* qkvA = (__half*)d_ws;                          // N*384 f16
  __half* qkvB = qkvA + (size_t)NCELL * 384;             // N*384 f16
  unsigned short* pQkv = (unsigned short*)(qkvB + (size_t)NCELL * 384);
  unsigned short* pOut = pQkv + 128 * 384;
  unsigned short* pFF1 = pOut + 128 * 128;
  unsigned short* pFF2 = pFF1 + 128 * 512;
  unsigned short* pHead= pFF2 + 512 * 128;

  packAll<<<dim3(104), dim3(256), 0, stream>>>(Wqkv, Wout, Wff1, Wff2, Whead,
                                               pQkv, pOut, pFF1, pFF2, pHead);
  nca_k1<<<dim3(864), dim3(256), 0, stream>>>(x0, ln1s, ln1b, pQkv, qkvA, steps, 0);
  // s=0: read qkvA, write next-step qkvB; s=1: read qkvB (tail skipped)
  nca_kA<<<dim3(864), dim3(512), 0, stream>>>(qkvA, qkvB, pQkv, pOut, bout,
                                              ln1s, ln1b, ln2s, ln2b, pFF1, bff1,
                                              pFF2, bff2, ln3s, ln3b, pHead, bhead,
                                              x0, out, steps, 0);
  nca_kA<<<dim3(864), dim3(512), 0, stream>>>(qkvB, qkvA, pQkv, pOut, bout,
                                              ln1s, ln1b, ln2s, ln2b, pFF1, bff1,
                                              pFF2, bff2, ln3s, ln3b, pHead, bhead,
                                              out, out, steps, 1);
}

// Round 11
// 112.555 us; speedup vs baseline: 1.1078x; 1.1078x over previous
//
#include <hip/hip_runtime.h>
#include <hip/hip_fp16.h>
#include <cstdint>
#include <cstddef>

// BasicViTNCA3D: 24^3 cells, C=128, 8 heads x dim16, MLP 512, 2 NCA steps.
// R11 = R9 (revert of R10's neighbor-slice regression) + micro-fixes:
//  - attention accumulators split 2-way (den, av0, av1) -> serial chain 27 -> ~14
//  - exp via exp2f with folded 0.25*log2(e) constant (drops 27 v_mul)
// R10 lesson: R9's channel-split keeps loads coalesced (4 lanes = one 32B K
// segment per neighbor); neighbor-split scattered them and regressed 20%.
#define NCELL 13824

typedef short bf16x8 __attribute__((ext_vector_type(8)));  // 8 bf16 (4 VGPRs)
typedef float f32x4  __attribute__((ext_vector_type(4)));  // MFMA acc
typedef _Float16 h2v __attribute__((ext_vector_type(2)));

__device__ __forceinline__ unsigned short f2bf(float x) {
  union { float f; uint32_t u; } c; c.f = x;
  uint32_t r = c.u + 0x7fffu + ((c.u >> 16) & 1u);  // RNE
  return (unsigned short)(r >> 16);
}

// A-fragment (16x32 tile, row = lane&15, k = (lane>>4)*8+j) from fp32 LDS row
__device__ __forceinline__ bf16x8 afrag_f32(const float* p) {
  float4 u0 = *(const float4*)p;
  float4 u1 = *(const float4*)(p + 4);
  bf16x8 a;
  a[0] = (short)f2bf(u0.x); a[1] = (short)f2bf(u0.y);
  a[2] = (short)f2bf(u0.z); a[3] = (short)f2bf(u0.w);
  a[4] = (short)f2bf(u1.x); a[5] = (short)f2bf(u1.y);
  a[6] = (short)f2bf(u1.z); a[7] = (short)f2bf(u1.w);
  return a;
}

// load 2x __half2 (8B) from f16 pointer
__device__ __forceinline__ void ldh2x2(const __half* p, __half2& a, __half2& b) {
  uint2 u = *(const uint2*)p;
  union { uint32_t u; __half2 h; } c0, c1;
  c0.u = u.x; c1.u = u.y;
  a = c0.h; b = c1.h;
}

// f32 += dot(half2, half2) via v_dot2_f32_f16 when available
__device__ __forceinline__ float fdot2(__half2 a, __half2 b, float c) {
#if __has_builtin(__builtin_amdgcn_fdot2)
  union { __half2 h; h2v n; } ua, ub;
  ua.h = a; ub.h = b;
  return __builtin_amdgcn_fdot2(ua.n, ub.n, c, false);
#else
  __half2 d = __hmul2(a, b);
  return c + __low2float(d) + __high2float(d);
#endif
}

// inf-safe tanh-form GELU (max abs dev ~1e-3 vs exact erf GELU)
__device__ __forceinline__ float gelu_f(float x) {
  float u = 0.7978845608f * x * (1.f + 0.044715f * x * x);
  float e = __expf(2.f * u);
  float t = 1.f - 2.f / (e + 1.f);   // tanh(u)
  return 0.5f * x * (1.f + t);
}

// ---------------- Threefry-2x32 (JAX-compatible) ----------------
__device__ __forceinline__ void tf2x32(uint32_t k0, uint32_t k1,
                                       uint32_t x0, uint32_t x1,
                                       uint32_t& o0, uint32_t& o1) {
  uint32_t k2 = k0 ^ k1 ^ 0x1BD11BDAu;
  x0 += k0; x1 += k1;
#define TFR(r) { x0 += x1; x1 = (x1 << (r)) | (x1 >> (32 - (r))); x1 ^= x0; }
  TFR(13) TFR(15) TFR(26) TFR(6)   x0 += k1; x1 += k2 + 1u;
  TFR(17) TFR(29) TFR(16) TFR(24)  x0 += k2; x1 += k0 + 2u;
  TFR(13) TFR(15) TFR(26) TFR(6)   x0 += k0; x1 += k1 + 3u;
  TFR(17) TFR(29) TFR(16) TFR(24)  x0 += k1; x1 += k2 + 4u;
  TFR(13) TFR(15) TFR(26) TFR(6)   x0 += k2; x1 += k0 + 5u;
#undef TFR
  o0 = x0; o1 = x1;
}

__device__ __forceinline__ float pe_val(int n, int c) {
  int dd = n % 24, ww = (n / 24) % 24, hh = n / 576;
  if (c == 126)
    return sinf((float)hh) + sinf(0.01f * (float)ww) + sinf(0.0001f * (float)dd);
  return cosf((float)hh) + cosf(0.01f * (float)ww) + cosf(0.0001f * (float)dd);
}

// ---------------- packAll: 5 weights -> MFMA B-frag bf16 ----------------
__device__ __forceinline__ void packOne(const float* __restrict__ W, int K, int N,
                                        unsigned short* __restrict__ P, int f) {
  int KT = K >> 5;
  int lane = f & 63;
  int ft = f >> 6;
  int kt = ft % KT, nt = ft / KT;
  int col = nt * 16 + (lane & 15);
  int k0 = kt * 32 + (lane >> 4) * 8;
  uint32_t w[4];
  #pragma unroll
  for (int p = 0; p < 4; ++p) {
    uint32_t lo = f2bf(W[(size_t)(k0 + 2 * p) * N + col]);
    uint32_t hi = f2bf(W[(size_t)(k0 + 2 * p + 1) * N + col]);
    w[p] = lo | (hi << 16);
  }
  uint4 v; v.x = w[0]; v.y = w[1]; v.z = w[2]; v.w = w[3];
  ((uint4*)P)[f] = v;
}

__global__ __launch_bounds__(256) void packAll(
    const float* __restrict__ Wqkv, const float* __restrict__ Wout,
    const float* __restrict__ Wff1, const float* __restrict__ Wff2,
    const float* __restrict__ Whead,
    unsigned short* __restrict__ pQkv, unsigned short* __restrict__ pOut,
    unsigned short* __restrict__ pFF1, unsigned short* __restrict__ pFF2,
    unsigned short* __restrict__ pHead) {
  int f = blockIdx.x * 256 + threadIdx.x;
  if (f < 6144)        packOne(Wqkv, 128, 384, pQkv, f);
  else if (f < 8192)   packOne(Wout, 128, 128, pOut, f - 6144);
  else if (f < 16384)  packOne(Wff1, 128, 512, pFF1, f - 8192);
  else if (f < 24576)  packOne(Wff2, 512, 128, pFF2, f - 16384);
  else if (f < 26624)  packOne(Whead, 128, 128, pHead, f - 24576);
}

// ---------------- K1: pe + LN1 + qkv GEMM (step 0 only) ----------------
__global__ __launch_bounds__(256) void nca_k1(
    const float* __restrict__ x, const float* __restrict__ ln1s,
    const float* __restrict__ ln1b, const unsigned short* __restrict__ pQkv,
    __half* __restrict__ wqkv,
    const int* __restrict__ steps, int s) {
  if (s >= *steps) return;
  __shared__ float ly[16][132];
  __shared__ float lmean[16], lrstd[16];
  const int t = threadIdx.x;
  const int swz = (blockIdx.x & 7) * 108 + (blockIdx.x >> 3);  // XCD-contiguous
  const int base = swz * 16;
  #pragma unroll
  for (int i = 0; i < 8; ++i) {
    int idx = i * 256 + t;
    int r = idx >> 7, c = idx & 127;
    int n = base + r;
    ly[r][c] = (c < 126) ? x[(size_t)n * 128 + c] : pe_val(n, c);
  }
  __syncthreads();
  { int r = t >> 4, j = t & 15;
    float s1 = 0.f, s2 = 0.f;
    #pragma unroll
    for (int cc = 0; cc < 8; ++cc) { float v = ly[r][j * 8 + cc]; s1 += v; s2 += v * v; }
    #pragma unroll
    for (int off = 1; off < 16; off <<= 1) { s1 += __shfl_xor(s1, off); s2 += __shfl_xor(s2, off); }
    if (j == 0) {
      float m = s1 * (1.f / 128.f);
      float var = s2 * (1.f / 128.f) - m * m;
      lmean[r] = m; lrstd[r] = rsqrtf(var + 1e-5f);
    }
  }
  __syncthreads();
  #pragma unroll
  for (int i = 0; i < 8; ++i) {
    int idx = i * 256 + t;
    int r = idx >> 7, c = idx & 127;
    ly[r][c] = (ly[r][c] - lmean[r]) * lrstd[r] * ln1s[c] + ln1b[c];
  }
  __syncthreads();
  const int w = t >> 6, l = t & 63;
  bf16x8 a4[4];
  #pragma unroll
  for (int kt = 0; kt < 4; ++kt)
    a4[kt] = afrag_f32(&ly[l & 15][kt * 32 + (l >> 4) * 8]);
  const bf16x8* B = (const bf16x8*)pQkv;
  #pragma unroll
  for (int q = 0; q < 6; ++q) {
    f32x4 acc = (f32x4){0.f, 0.f, 0.f, 0.f};
    int nt = w * 6 + q;
    #pragma unroll
    for (int kt = 0; kt < 4; ++kt)
      acc = __builtin_amdgcn_mfma_f32_16x16x32_bf16(a4[kt], B[(nt * 4 + kt) * 64 + l], acc, 0, 0, 0);
    int col = nt * 16 + (l & 15);
    #pragma unroll
    for (int j = 0; j < 4; ++j)
      wqkv[(size_t)(base + (l >> 4) * 4 + j) * 384 + col] = __float2half(acc[j]);
  }
}

// ---- kA: attn + out-proj + LN2 + FF1 + FF2 + LN3 + head + mask-update + next qkv ----
__global__ __launch_bounds__(512, 4) void nca_kA(
    const __half* __restrict__ qkv, __half* __restrict__ qkvN,
    const unsigned short* __restrict__ pQkv,
    const unsigned short* __restrict__ pOut, const float* __restrict__ bout,
    const float* __restrict__ ln1s, const float* __restrict__ ln1b,
    const float* __restrict__ ln2s, const float* __restrict__ ln2b,
    const unsigned short* __restrict__ pFF1, const float* __restrict__ bff1,
    const unsigned short* __restrict__ pFF2, const float* __restrict__ bff2,
    const float* __restrict__ ln3s, const float* __restrict__ ln3b,
    const unsigned short* __restrict__ pHead, const float* __restrict__ bhead,
    const float* __restrict__ xin, float* __restrict__ xout,
    const int* __restrict__ steps, int s) {
  if (s >= *steps) return;
  __shared__ unsigned short lnorm[16][136];  // bf16: attn-out / ln2 / ln3 / ln1'
  __shared__ float ly2[16][132];             // f32: y2 -> y3 (in place) -> x_new
  __shared__ unsigned short lh[16][520];     // bf16: GELU(FF1)
  __shared__ float lmask[16];
  const int t = threadIdx.x;
  const int swz = (blockIdx.x & 7) * 108 + (blockIdx.x >> 3);  // XCD-contiguous
  const int base = swz * 16;
  const int w = t >> 6, l = t & 63;
  const int lr = (l >> 4) * 4, lc = l & 15;

  // prefetch residual x for this thread's GEMM output slots (consumed post-barrier)
  float xres[4];
  {
    int col = w * 16 + lc;
    #pragma unroll
    for (int j = 0; j < 4; ++j)
      xres[j] = xin[(size_t)(base + lr + j) * 128 + col];
  }
  if (t < 16) { // JAX threefry per-cell mask (partitionable random_bits)
    uint32_t kk0, kk1, b0, b1;
    tf2x32(0u, 42u, 0u, (uint32_t)s, kk0, kk1);
    tf2x32(kk0, kk1, 0u, (uint32_t)(base + t), b0, b1);
    uint32_t bits = b0 ^ b1;
    lmask[t] = ((bits >> 9) > 0x400000u) ? 1.0f : 0.0f;
  }
  // ---- attention: 16 cells x 8 heads x 4 quarters = 512 threads ----
  // fused loop, clamp-addressed unconditional loads, arithmetic OOB masking;
  // 2-way split accumulators shorten the serial chain.
  {
    const int cell = t >> 5, head = (t >> 2) & 7, qr = t & 3;
    const int n = base + cell;
    const int dd = n % 24, ww = (n / 24) % 24, hh = n / 576;
    const int qoff = head * 16 + qr * 4;
    __half2 q0, q1;
    ldh2x2(qkv + (size_t)n * 384 + qoff, q0, q1);
    const __half* kb = qkv + 128 + qoff;     // + nn*384 per neighbor
    const __half2 hz = __float2half2_rn(0.f);
    float denA = 0.f, denB = 0.f;
    __half2 av0A = hz, av1A = hz, av0B = hz, av1B = hz;
    int par = 0;
    #pragma unroll
    for (int di = -1; di <= 1; ++di) {
      int hh2 = hh + di;
      bool okh = (unsigned)hh2 < 24u;
      int hc = min(max(hh2, 0), 23) * 576;
      #pragma unroll
      for (int dj = -1; dj <= 1; ++dj) {
        int ww2 = ww + dj;
        bool okw = okh && ((unsigned)ww2 < 24u);
        int wc = hc + min(max(ww2, 0), 23) * 24;
        #pragma unroll
        for (int dk = -1; dk <= 1; ++dk) {
          int dd2 = dd + dk;
          bool ok = okw && ((unsigned)dd2 < 24u);
          int nn = wc + min(max(dd2, 0), 23);
          const __half* kp = kb + (size_t)nn * 384;
          __half2 k0, k1, v0, v1;
          ldh2x2(kp, k0, k1);          // unconditional (clamped -> in range)
          ldh2x2(kp + 128, v0, v1);    // V row
          float dotc = fdot2(q1, k1, fdot2(q0, k0, 0.f));
          float dot = ok ? dotc : 0.f;
          dot += __shfl_xor(dot, 1);
          dot += __shfl_xor(dot, 2);   // full 16-ch dot in all 4 lanes
          float e = exp2f(dot * 0.36067376f);  // exp(dot*0.25); OOB -> 1
          float em = ok ? e : 0.f;             // OOB contributes nothing to PV
          __half2 e2 = __float2half2_rn(em);
          if (par) {
            denB += e;
            av0B = __hfma2(e2, v0, av0B);
            av1B = __hfma2(e2, v1, av1B);
          } else {
            denA += e;
            av0A = __hfma2(e2, v0, av0A);
            av1A = __hfma2(e2, v1, av1A);
          }
          par ^= 1;
        }
      }
    }
    float den = denA + denB;
    __half2 av0 = __hadd2(av0A, av0B), av1 = __hadd2(av1A, av1B);
    float inv = 1.f / den;
    float2 f0 = __half22float2(av0), f1 = __half22float2(av1);
    uint32_t w0 = (uint32_t)f2bf(f0.x * inv) | ((uint32_t)f2bf(f0.y * inv) << 16);
    uint32_t w1 = (uint32_t)f2bf(f1.x * inv) | ((uint32_t)f2bf(f1.y * inv) << 16);
    *(uint2*)&lnorm[cell][qoff] = (uint2){w0, w1};
  }
  __syncthreads();
  // ---- out-proj: wave w -> coltile w; epilogue y2 -> ly2 (f32) ----
  bf16x8 a4[4];
  #pragma unroll
  for (int kt = 0; kt < 4; ++kt)
    a4[kt] = *(const bf16x8*)&lnorm[l & 15][kt * 32 + (l >> 4) * 8];
  {
    f32x4 acc = (f32x4){0.f,0.f,0.f,0.f};
    const bf16x8* B = (const bf16x8*)pOut;
    #pragma unroll
    for (int kt = 0; kt < 4; ++kt)
      acc = __builtin_amdgcn_mfma_f32_16x16x32_bf16(a4[kt], B[(w * 4 + kt) * 64 + l], acc, 0, 0, 0);
    int col = w * 16 + lc;
    #pragma unroll
    for (int j = 0; j < 4; ++j) {
      int r = lr + j, n = base + r;
      float resy = (col < 126) ? xres[j] : pe_val(n, col);  // y residual has pe
      ly2[r][col] = acc[j] + bout[col] + resy;
    }
  }
  __syncthreads();
  { // ---- LN2: butterfly stats + normalize own 4 ch -> lnorm bf16 ----
    int r = t >> 5, j = t & 31;
    float v0 = ly2[r][j*4], v1 = ly2[r][j*4+1], v2 = ly2[r][j*4+2], v3 = ly2[r][j*4+3];
    float s1 = v0 + v1 + v2 + v3;
    float s2 = v0*v0 + v1*v1 + v2*v2 + v3*v3;
    #pragma unroll
    for (int off = 1; off < 32; off <<= 1) { s1 += __shfl_xor(s1, off); s2 += __shfl_xor(s2, off); }
    float m = s1 * (1.f / 128.f);
    float rstd = rsqrtf(s2 * (1.f / 128.f) - m * m + 1e-5f);
    float n0 = (v0 - m) * rstd * ln2s[j*4]   + ln2b[j*4];
    float n1 = (v1 - m) * rstd * ln2s[j*4+1] + ln2b[j*4+1];
    float n2 = (v2 - m) * rstd * ln2s[j*4+2] + ln2b[j*4+2];
    float n3 = (v3 - m) * rstd * ln2s[j*4+3] + ln2b[j*4+3];
    uint32_t w0 = (uint32_t)f2bf(n0) | ((uint32_t)f2bf(n1) << 16);
    uint32_t w1 = (uint32_t)f2bf(n2) | ((uint32_t)f2bf(n3) << 16);
    *(uint2*)&lnorm[r][j * 4] = (uint2){w0, w1};
  }
  __syncthreads();
  // ---- FF1: wave w -> coltiles w*4..w*4+3; fast GELU -> lh bf16 ----
  #pragma unroll
  for (int kt = 0; kt < 4; ++kt)
    a4[kt] = *(const bf16x8*)&lnorm[l & 15][kt * 32 + (l >> 4) * 8];
  {
    f32x4 acc[4];
    #pragma unroll
    for (int q = 0; q < 4; ++q) acc[q] = (f32x4){0.f,0.f,0.f,0.f};
    const bf16x8* B = (const bf16x8*)pFF1;
    #pragma unroll
    for (int kt = 0; kt < 4; ++kt) {
      #pragma unroll
      for (int q = 0; q < 4; ++q) {
        int nt = w * 4 + q;
        acc[q] = __builtin_amdgcn_mfma_f32_16x16x32_bf16(a4[kt], B[(nt * 4 + kt) * 64 + l], acc[q], 0, 0, 0);
      }
    }
    #pragma unroll
    for (int q = 0; q < 4; ++q) {
      int col = (w * 4 + q) * 16 + lc;
      #pragma unroll
      for (int j = 0; j < 4; ++j)
        lh[lr + j][col] = f2bf(gelu_f(acc[q][j] + bff1[col]));
    }
  }
  __syncthreads();
  // ---- FF2: K=512, wave w -> coltile w; y3 = acc + b + y2 in place (owner) ----
  {
    f32x4 acc = (f32x4){0.f,0.f,0.f,0.f};
    const bf16x8* B = (const bf16x8*)pFF2;
    #pragma unroll
    for (int kt = 0; kt < 16; ++kt) {
      bf16x8 a = *(const bf16x8*)&lh[l & 15][kt * 32 + (l >> 4) * 8];
      acc = __builtin_amdgcn_mfma_f32_16x16x32_bf16(a, B[(w * 16 + kt) * 64 + l], acc, 0, 0, 0);
    }
    int col = w * 16 + lc;
    #pragma unroll
    for (int j = 0; j < 4; ++j) {
      int r = lr + j;
      ly2[r][col] = acc[j] + bff2[col] + ly2[r][col];
    }
  }
  __syncthreads();
  { // ---- LN3: butterfly stats + normalize -> lnorm bf16 ----
    int r = t >> 5, j = t & 31;
    float v0 = ly2[r][j*4], v1 = ly2[r][j*4+1], v2 = ly2[r][j*4+2], v3 = ly2[r][j*4+3];
    float s1 = v0 + v1 + v2 + v3;
    float s2 = v0*v0 + v1*v1 + v2*v2 + v3*v3;
    #pragma unroll
    for (int off = 1; off < 32; off <<= 1) { s1 += __shfl_xor(s1, off); s2 += __shfl_xor(s2, off); }
    float m = s1 * (1.f / 128.f);
    float rstd = rsqrtf(s2 * (1.f / 128.f) - m * m + 1e-5f);
    float n0 = (v0 - m) * rstd * ln3s[j*4]   + ln3b[j*4];
    float n1 = (v1 - m) * rstd * ln3s[j*4+1] + ln3b[j*4+1];
    float n2 = (v2 - m) * rstd * ln3s[j*4+2] + ln3b[j*4+2];
    float n3 = (v3 - m) * rstd * ln3s[j*4+3] + ln3b[j*4+3];
    uint32_t w0 = (uint32_t)f2bf(n0) | ((uint32_t)f2bf(n1) << 16);
    uint32_t w1 = (uint32_t)f2bf(n2) | ((uint32_t)f2bf(n3) << 16);
    *(uint2*)&lnorm[r][j * 4] = (uint2){w0, w1};
  }
  __syncthreads();
  // ---- head: wave w -> coltile w; dx; masked update; x_new -> ly2 ----
  #pragma unroll
  for (int kt = 0; kt < 4; ++kt)
    a4[kt] = *(const bf16x8*)&lnorm[l & 15][kt * 32 + (l >> 4) * 8];
  {
    f32x4 acc = (f32x4){0.f,0.f,0.f,0.f};
    const bf16x8* B = (const bf16x8*)pHead;
    #pragma unroll
    for (int kt = 0; kt < 4; ++kt)
      acc = __builtin_amdgcn_mfma_f32_16x16x32_bf16(a4[kt], B[(w * 4 + kt) * 64 + l], acc, 0, 0, 0);
    int col = w * 16 + lc;
    #pragma unroll
    for (int j = 0; j < 4; ++j) {
      int r = lr + j;
      size_t n = base + r;
      float dx = acc[j] + bhead[col];
      float xn = xres[j] + dx * lmask[r];
      xout[n * 128 + col] = xn;
      ly2[r][col] = xn;
    }
  }
  // ---- tail: next step's pe + LN1 + qkv GEMM (skipped on last step) ----
  if (s + 1 < *steps) {
    __syncthreads();
    if (t < 32) { int r = t >> 1, c = 126 + (t & 1); ly2[r][c] = pe_val(base + r, c); }
    __syncthreads();
    { // LN1: butterfly stats + normalize -> lnorm bf16
      int r = t >> 5, j = t & 31;
      float v0 = ly2[r][j*4], v1 = ly2[r][j*4+1], v2 = ly2[r][j*4+2], v3 = ly2[r][j*4+3];
      float s1 = v0 + v1 + v2 + v3;
      float s2 = v0*v0 + v1*v1 + v2*v2 + v3*v3;
      #pragma unroll
      for (int off = 1; off < 32; off <<= 1) { s1 += __shfl_xor(s1, off); s2 += __shfl_xor(s2, off); }
      float m = s1 * (1.f / 128.f);
      float rstd = rsqrtf(s2 * (1.f / 128.f) - m * m + 1e-5f);
      float n0 = (v0 - m) * rstd * ln1s[j*4]   + ln1b[j*4];
      float n1 = (v1 - m) * rstd * ln1s[j*4+1] + ln1b[j*4+1];
      float n2 = (v2 - m) * rstd * ln1s[j*4+2] + ln1b[j*4+2];
      float n3 = (v3 - m) * rstd * ln1s[j*4+3] + ln1b[j*4+3];
      uint32_t w0 = (uint32_t)f2bf(n0) | ((uint32_t)f2bf(n1) << 16);
      uint32_t w1 = (uint32_t)f2bf(n2) | ((uint32_t)f2bf(n3) << 16);
      *(uint2*)&lnorm[r][j * 4] = (uint2){w0, w1};
    }
    __syncthreads();
    #pragma unroll
    for (int kt = 0; kt < 4; ++kt)
      a4[kt] = *(const bf16x8*)&lnorm[l & 15][kt * 32 + (l >> 4) * 8];
    const bf16x8* B = (const bf16x8*)pQkv;
    #pragma unroll
    for (int q = 0; q < 3; ++q) {
      f32x4 acc = (f32x4){0.f,0.f,0.f,0.f};
      int nt = w * 3 + q;
      #pragma unroll
      for (int kt = 0; kt < 4; ++kt)
        acc = __builtin_amdgcn_mfma_f32_16x16x32_bf16(a4[kt], B[(nt * 4 + kt) * 64 + l], acc, 0, 0, 0);
      int col = nt * 16 + lc;
      #pragma unroll
      for (int j = 0; j < 4; ++j)
        qkvN[(size_t)(base + lr + j) * 384 + col] = __float2half(acc[j]);
    }
  }
}

extern "C" void kernel_launch(void* const* d_in, const int* in_sizes, int n_in,
                              void* d_out, int out_size, void* d_ws, size_t ws_size,
                              hipStream_t stream) {
  const float* x0   = (const float*)d_in[0];
  const float* Wqkv = (const float*)d_in[1];
  const float* Wout = (const float*)d_in[2];
  const float* bout = (const float*)d_in[3];
  const float* ln1s = (const float*)d_in[4];
  const float* ln1b = (const float*)d_in[5];
  const float* Wff1 = (const float*)d_in[6];
  const float* bff1 = (const float*)d_in[7];
  const float* Wff2 = (const float*)d_in[8];
  const float* bff2 = (const float*)d_in[9];
  const float* ln2s = (const float*)d_in[10];
  const float* ln2b = (const float*)d_in[11];
  const float* ln3s = (const float*)d_in[12];
  const float* ln3b = (const float*)d_in[13];
  const float* Whead= (const float*)d_in[14];
  const float* bhead= (const float*)d_in[15];
  const int*   steps= (const int*)d_in[16];
  float* out = (float*)d_out;

  __half* qkvA = (__half*)d_ws;                          // N*384 f16
  __half* qkvB = qkvA + (size_t)NCELL * 384;             // N*384 f16
  unsigned short* pQkv = (unsigned short*)(qkvB + (size_t)NCELL * 384);
  unsigned short* pOut = pQkv + 128 * 384;
  unsigned short* pFF1 = pOut + 128 * 128;
  unsigned short* pFF2 = pFF1 + 128 * 512;
  unsigned short* pHead= pFF2 + 512 * 128;

  packAll<<<dim3(104), dim3(256), 0, stream>>>(Wqkv, Wout, Wff1, Wff2, Whead,
                                               pQkv, pOut, pFF1, pFF2, pHead);
  nca_k1<<<dim3(864), dim3(256), 0, stream>>>(x0, ln1s, ln1b, pQkv, qkvA, steps, 0);
  // s=0: read qkvA, write next-step qkvB; s=1: read qkvB (tail skipped)
  nca_kA<<<dim3(864), dim3(512), 0, stream>>>(qkvA, qkvB, pQkv, pOut, bout,
                                              ln1s, ln1b, ln2s, ln2b, pFF1, bff1,
                                              pFF2, bff2, ln3s, ln3b, pHead, bhead,
                                              x0, out, steps, 0);
  nca_kA<<<dim3(864), dim3(512), 0, stream>>>(qkvB, qkvA, pQkv, pOut, bout,
                                              ln1s, ln1b, ln2s, ln2b, pFF1, bff1,
                                              pFF2, bff2, ln3s, ln3b, pHead, bhead,
                                              out, out, steps, 1);
}

// Round 12
// 104.119 us; speedup vs baseline: 1.1976x; 1.0810x over previous
//
#include <hip/hip_runtime.h>
#include <hip/hip_fp16.h>
#include <cstdint>
#include <cstddef>

// BasicViTNCA3D: 24^3 cells, C=128, 8 heads x dim16, MLP 512, 2 NCA steps.
// R12 = exact revert to R9 (best measured: 104.2 us total, kA 48.2 us).
// R10 (neighbor-split) and R11 (split accumulators) both regressed:
//  - R10: scattered loads, longer per-neighbor dot chain -> +20%
//  - R11: 6 live accumulators across 27-deep unrolled loop -> scratch spill
//    (WRITE_SIZE 17.3 -> 29.3 MB), +12% on kA.
// R9 structure: clamp-addressed unconditional K/V loads (hoistable batch),
// arithmetic OOB masking, fdot2 QK dots, no max-sub softmax, fused single
// 27-neighbor loop, xres prefetch, bf16-LDS GEMM phases, fused step tail.
#define NCELL 13824

typedef short bf16x8 __attribute__((ext_vector_type(8)));  // 8 bf16 (4 VGPRs)
typedef float f32x4  __attribute__((ext_vector_type(4)));  // MFMA acc
typedef _Float16 h2v __attribute__((ext_vector_type(2)));

__device__ __forceinline__ unsigned short f2bf(float x) {
  union { float f; uint32_t u; } c; c.f = x;
  uint32_t r = c.u + 0x7fffu + ((c.u >> 16) & 1u);  // RNE
  return (unsigned short)(r >> 16);
}

// A-fragment (16x32 tile, row = lane&15, k = (lane>>4)*8+j) from fp32 LDS row
__device__ __forceinline__ bf16x8 afrag_f32(const float* p) {
  float4 u0 = *(const float4*)p;
  float4 u1 = *(const float4*)(p + 4);
  bf16x8 a;
  a[0] = (short)f2bf(u0.x); a[1] = (short)f2bf(u0.y);
  a[2] = (short)f2bf(u0.z); a[3] = (short)f2bf(u0.w);
  a[4] = (short)f2bf(u1.x); a[5] = (short)f2bf(u1.y);
  a[6] = (short)f2bf(u1.z); a[7] = (short)f2bf(u1.w);
  return a;
}

// load 2x __half2 (8B) from f16 pointer
__device__ __forceinline__ void ldh2x2(const __half* p, __half2& a, __half2& b) {
  uint2 u = *(const uint2*)p;
  union { uint32_t u; __half2 h; } c0, c1;
  c0.u = u.x; c1.u = u.y;
  a = c0.h; b = c1.h;
}

// f32 += dot(half2, half2) via v_dot2_f32_f16 when available
__device__ __forceinline__ float fdot2(__half2 a, __half2 b, float c) {
#if __has_builtin(__builtin_amdgcn_fdot2)
  union { __half2 h; h2v n; } ua, ub;
  ua.h = a; ub.h = b;
  return __builtin_amdgcn_fdot2(ua.n, ub.n, c, false);
#else
  __half2 d = __hmul2(a, b);
  return c + __low2float(d) + __high2float(d);
#endif
}

// inf-safe tanh-form GELU (max abs dev ~1e-3 vs exact erf GELU)
__device__ __forceinline__ float gelu_f(float x) {
  float u = 0.7978845608f * x * (1.f + 0.044715f * x * x);
  float e = __expf(2.f * u);
  float t = 1.f - 2.f / (e + 1.f);   // tanh(u)
  return 0.5f * x * (1.f + t);
}

// ---------------- Threefry-2x32 (JAX-compatible) ----------------
__device__ __forceinline__ void tf2x32(uint32_t k0, uint32_t k1,
                                       uint32_t x0, uint32_t x1,
                                       uint32_t& o0, uint32_t& o1) {
  uint32_t k2 = k0 ^ k1 ^ 0x1BD11BDAu;
  x0 += k0; x1 += k1;
#define TFR(r) { x0 += x1; x1 = (x1 << (r)) | (x1 >> (32 - (r))); x1 ^= x0; }
  TFR(13) TFR(15) TFR(26) TFR(6)   x0 += k1; x1 += k2 + 1u;
  TFR(17) TFR(29) TFR(16) TFR(24)  x0 += k2; x1 += k0 + 2u;
  TFR(13) TFR(15) TFR(26) TFR(6)   x0 += k0; x1 += k1 + 3u;
  TFR(17) TFR(29) TFR(16) TFR(24)  x0 += k1; x1 += k2 + 4u;
  TFR(13) TFR(15) TFR(26) TFR(6)   x0 += k2; x1 += k0 + 5u;
#undef TFR
  o0 = x0; o1 = x1;
}

__device__ __forceinline__ float pe_val(int n, int c) {
  int dd = n % 24, ww = (n / 24) % 24, hh = n / 576;
  if (c == 126)
    return sinf((float)hh) + sinf(0.01f * (float)ww) + sinf(0.0001f * (float)dd);
  return cosf((float)hh) + cosf(0.01f * (float)ww) + cosf(0.0001f * (float)dd);
}

// ---------------- packAll: 5 weights -> MFMA B-frag bf16 ----------------
__device__ __forceinline__ void packOne(const float* __restrict__ W, int K, int N,
                                        unsigned short* __restrict__ P, int f) {
  int KT = K >> 5;
  int lane = f & 63;
  int ft = f >> 6;
  int kt = ft % KT, nt = ft / KT;
  int col = nt * 16 + (lane & 15);
  int k0 = kt * 32 + (lane >> 4) * 8;
  uint32_t w[4];
  #pragma unroll
  for (int p = 0; p < 4; ++p) {
    uint32_t lo = f2bf(W[(size_t)(k0 + 2 * p) * N + col]);
    uint32_t hi = f2bf(W[(size_t)(k0 + 2 * p + 1) * N + col]);
    w[p] = lo | (hi << 16);
  }
  uint4 v; v.x = w[0]; v.y = w[1]; v.z = w[2]; v.w = w[3];
  ((uint4*)P)[f] = v;
}

__global__ __launch_bounds__(256) void packAll(
    const float* __restrict__ Wqkv, const float* __restrict__ Wout,
    const float* __restrict__ Wff1, const float* __restrict__ Wff2,
    const float* __restrict__ Whead,
    unsigned short* __restrict__ pQkv, unsigned short* __restrict__ pOut,
    unsigned short* __restrict__ pFF1, unsigned short* __restrict__ pFF2,
    unsigned short* __restrict__ pHead) {
  int f = blockIdx.x * 256 + threadIdx.x;
  if (f < 6144)        packOne(Wqkv, 128, 384, pQkv, f);
  else if (f < 8192)   packOne(Wout, 128, 128, pOut, f - 6144);
  else if (f < 16384)  packOne(Wff1, 128, 512, pFF1, f - 8192);
  else if (f < 24576)  packOne(Wff2, 512, 128, pFF2, f - 16384);
  else if (f < 26624)  packOne(Whead, 128, 128, pHead, f - 24576);
}

// ---------------- K1: pe + LN1 + qkv GEMM (step 0 only) ----------------
__global__ __launch_bounds__(256) void nca_k1(
    const float* __restrict__ x, const float* __restrict__ ln1s,
    const float* __restrict__ ln1b, const unsigned short* __restrict__ pQkv,
    __half* __restrict__ wqkv,
    const int* __restrict__ steps, int s) {
  if (s >= *steps) return;
  __shared__ float ly[16][132];
  __shared__ float lmean[16], lrstd[16];
  const int t = threadIdx.x;
  const int swz = (blockIdx.x & 7) * 108 + (blockIdx.x >> 3);  // XCD-contiguous
  const int base = swz * 16;
  #pragma unroll
  for (int i = 0; i < 8; ++i) {
    int idx = i * 256 + t;
    int r = idx >> 7, c = idx & 127;
    int n = base + r;
    ly[r][c] = (c < 126) ? x[(size_t)n * 128 + c] : pe_val(n, c);
  }
  __syncthreads();
  { int r = t >> 4, j = t & 15;
    float s1 = 0.f, s2 = 0.f;
    #pragma unroll
    for (int cc = 0; cc < 8; ++cc) { float v = ly[r][j * 8 + cc]; s1 += v; s2 += v * v; }
    #pragma unroll
    for (int off = 1; off < 16; off <<= 1) { s1 += __shfl_xor(s1, off); s2 += __shfl_xor(s2, off); }
    if (j == 0) {
      float m = s1 * (1.f / 128.f);
      float var = s2 * (1.f / 128.f) - m * m;
      lmean[r] = m; lrstd[r] = rsqrtf(var + 1e-5f);
    }
  }
  __syncthreads();
  #pragma unroll
  for (int i = 0; i < 8; ++i) {
    int idx = i * 256 + t;
    int r = idx >> 7, c = idx & 127;
    ly[r][c] = (ly[r][c] - lmean[r]) * lrstd[r] * ln1s[c] + ln1b[c];
  }
  __syncthreads();
  const int w = t >> 6, l = t & 63;
  bf16x8 a4[4];
  #pragma unroll
  for (int kt = 0; kt < 4; ++kt)
    a4[kt] = afrag_f32(&ly[l & 15][kt * 32 + (l >> 4) * 8]);
  const bf16x8* B = (const bf16x8*)pQkv;
  #pragma unroll
  for (int q = 0; q < 6; ++q) {
    f32x4 acc = (f32x4){0.f, 0.f, 0.f, 0.f};
    int nt = w * 6 + q;
    #pragma unroll
    for (int kt = 0; kt < 4; ++kt)
      acc = __builtin_amdgcn_mfma_f32_16x16x32_bf16(a4[kt], B[(nt * 4 + kt) * 64 + l], acc, 0, 0, 0);
    int col = nt * 16 + (l & 15);
    #pragma unroll
    for (int j = 0; j < 4; ++j)
      wqkv[(size_t)(base + (l >> 4) * 4 + j) * 384 + col] = __float2half(acc[j]);
  }
}

// ---- kA: attn + out-proj + LN2 + FF1 + FF2 + LN3 + head + mask-update + next qkv ----
__global__ __launch_bounds__(512, 4) void nca_kA(
    const __half* __restrict__ qkv, __half* __restrict__ qkvN,
    const unsigned short* __restrict__ pQkv,
    const unsigned short* __restrict__ pOut, const float* __restrict__ bout,
    const float* __restrict__ ln1s, const float* __restrict__ ln1b,
    const float* __restrict__ ln2s, const float* __restrict__ ln2b,
    const unsigned short* __restrict__ pFF1, const float* __restrict__ bff1,
    const unsigned short* __restrict__ pFF2, const float* __restrict__ bff2,
    const float* __restrict__ ln3s, const float* __restrict__ ln3b,
    const unsigned short* __restrict__ pHead, const float* __restrict__ bhead,
    const float* __restrict__ xin, float* __restrict__ xout,
    const int* __restrict__ steps, int s) {
  if (s >= *steps) return;
  __shared__ unsigned short lnorm[16][136];  // bf16: attn-out / ln2 / ln3 / ln1'
  __shared__ float ly2[16][132];             // f32: y2 -> y3 (in place) -> x_new
  __shared__ unsigned short lh[16][520];     // bf16: GELU(FF1)
  __shared__ float lmask[16];
  const int t = threadIdx.x;
  const int swz = (blockIdx.x & 7) * 108 + (blockIdx.x >> 3);  // XCD-contiguous
  const int base = swz * 16;
  const int w = t >> 6, l = t & 63;
  const int lr = (l >> 4) * 4, lc = l & 15;

  // prefetch residual x for this thread's GEMM output slots (consumed post-barrier)
  float xres[4];
  {
    int col = w * 16 + lc;
    #pragma unroll
    for (int j = 0; j < 4; ++j)
      xres[j] = xin[(size_t)(base + lr + j) * 128 + col];
  }
  if (t < 16) { // JAX threefry per-cell mask (partitionable random_bits)
    uint32_t kk0, kk1, b0, b1;
    tf2x32(0u, 42u, 0u, (uint32_t)s, kk0, kk1);
    tf2x32(kk0, kk1, 0u, (uint32_t)(base + t), b0, b1);
    uint32_t bits = b0 ^ b1;
    lmask[t] = ((bits >> 9) > 0x400000u) ? 1.0f : 0.0f;
  }
  // ---- attention: 16 cells x 8 heads x 4 quarters = 512 threads ----
  // fused loop, clamp-addressed unconditional loads, arithmetic OOB masking
  {
    const int cell = t >> 5, head = (t >> 2) & 7, qr = t & 3;
    const int n = base + cell;
    const int dd = n % 24, ww = (n / 24) % 24, hh = n / 576;
    const int qoff = head * 16 + qr * 4;
    __half2 q0, q1;
    ldh2x2(qkv + (size_t)n * 384 + qoff, q0, q1);
    const __half* kb = qkv + 128 + qoff;     // + nn*384 per neighbor
    const __half2 hz = __float2half2_rn(0.f);
    float den = 0.f;
    __half2 av0 = hz, av1 = hz;
    #pragma unroll
    for (int di = -1; di <= 1; ++di) {
      int hh2 = hh + di;
      bool okh = (unsigned)hh2 < 24u;
      int hc = min(max(hh2, 0), 23) * 576;
      #pragma unroll
      for (int dj = -1; dj <= 1; ++dj) {
        int ww2 = ww + dj;
        bool okw = okh && ((unsigned)ww2 < 24u);
        int wc = hc + min(max(ww2, 0), 23) * 24;
        #pragma unroll
        for (int dk = -1; dk <= 1; ++dk) {
          int dd2 = dd + dk;
          bool ok = okw && ((unsigned)dd2 < 24u);
          int nn = wc + min(max(dd2, 0), 23);
          const __half* kp = kb + (size_t)nn * 384;
          __half2 k0, k1, v0, v1;
          ldh2x2(kp, k0, k1);          // unconditional (clamped -> in range)
          ldh2x2(kp + 128, v0, v1);    // V row
          float dotc = fdot2(q1, k1, fdot2(q0, k0, 0.f));
          float dot = ok ? dotc : 0.f;
          dot += __shfl_xor(dot, 1);
          dot += __shfl_xor(dot, 2);   // full 16-ch dot in all 4 lanes
          float e = __expf(dot * 0.25f);  // OOB -> dot 0 -> e = 1 (zero-pad softmax)
          den += e;
          float em = ok ? e : 0.f;        // OOB contributes nothing to PV
          __half2 e2 = __float2half2_rn(em);
          av0 = __hfma2(e2, v0, av0);
          av1 = __hfma2(e2, v1, av1);
        }
      }
    }
    float inv = 1.f / den;
    float2 f0 = __half22float2(av0), f1 = __half22float2(av1);
    uint32_t w0 = (uint32_t)f2bf(f0.x * inv) | ((uint32_t)f2bf(f0.y * inv) << 16);
    uint32_t w1 = (uint32_t)f2bf(f1.x * inv) | ((uint32_t)f2bf(f1.y * inv) << 16);
    *(uint2*)&lnorm[cell][qoff] = (uint2){w0, w1};
  }
  __syncthreads();
  // ---- out-proj: wave w -> coltile w; epilogue y2 -> ly2 (f32) ----
  bf16x8 a4[4];
  #pragma unroll
  for (int kt = 0; kt < 4; ++kt)
    a4[kt] = *(const bf16x8*)&lnorm[l & 15][kt * 32 + (l >> 4) * 8];
  {
    f32x4 acc = (f32x4){0.f,0.f,0.f,0.f};
    const bf16x8* B = (const bf16x8*)pOut;
    #pragma unroll
    for (int kt = 0; kt < 4; ++kt)
      acc = __builtin_amdgcn_mfma_f32_16x16x32_bf16(a4[kt], B[(w * 4 + kt) * 64 + l], acc, 0, 0, 0);
    int col = w * 16 + lc;
    #pragma unroll
    for (int j = 0; j < 4; ++j) {
      int r = lr + j, n = base + r;
      float resy = (col < 126) ? xres[j] : pe_val(n, col);  // y residual has pe
      ly2[r][col] = acc[j] + bout[col] + resy;
    }
  }
  __syncthreads();
  { // ---- LN2: butterfly stats + normalize own 4 ch -> lnorm bf16 ----
    int r = t >> 5, j = t & 31;
    float v0 = ly2[r][j*4], v1 = ly2[r][j*4+1], v2 = ly2[r][j*4+2], v3 = ly2[r][j*4+3];
    float s1 = v0 + v1 + v2 + v3;
    float s2 = v0*v0 + v1*v1 + v2*v2 + v3*v3;
    #pragma unroll
    for (int off = 1; off < 32; off <<= 1) { s1 += __shfl_xor(s1, off); s2 += __shfl_xor(s2, off); }
    float m = s1 * (1.f / 128.f);
    float rstd = rsqrtf(s2 * (1.f / 128.f) - m * m + 1e-5f);
    float n0 = (v0 - m) * rstd * ln2s[j*4]   + ln2b[j*4];
    float n1 = (v1 - m) * rstd * ln2s[j*4+1] + ln2b[j*4+1];
    float n2 = (v2 - m) * rstd * ln2s[j*4+2] + ln2b[j*4+2];
    float n3 = (v3 - m) * rstd * ln2s[j*4+3] + ln2b[j*4+3];
    uint32_t w0 = (uint32_t)f2bf(n0) | ((uint32_t)f2bf(n1) << 16);
    uint32_t w1 = (uint32_t)f2bf(n2) | ((uint32_t)f2bf(n3) << 16);
    *(uint2*)&lnorm[r][j * 4] = (uint2){w0, w1};
  }
  __syncthreads();
  // ---- FF1: wave w -> coltiles w*4..w*4+3; fast GELU -> lh bf16 ----
  #pragma unroll
  for (int kt = 0; kt < 4; ++kt)
    a4[kt] = *(const bf16x8*)&lnorm[l & 15][kt * 32 + (l >> 4) * 8];
  {
    f32x4 acc[4];
    #pragma unroll
    for (int q = 0; q < 4; ++q) acc[q] = (f32x4){0.f,0.f,0.f,0.f};
    const bf16x8* B = (const bf16x8*)pFF1;
    #pragma unroll
    for (int kt = 0; kt < 4; ++kt) {
      #pragma unroll
      for (int q = 0; q < 4; ++q) {
        int nt = w * 4 + q;
        acc[q] = __builtin_amdgcn_mfma_f32_16x16x32_bf16(a4[kt], B[(nt * 4 + kt) * 64 + l], acc[q], 0, 0, 0);
      }
    }
    #pragma unroll
    for (int q = 0; q < 4; ++q) {
      int col = (w * 4 + q) * 16 + lc;
      #pragma unroll
      for (int j = 0; j < 4; ++j)
        lh[lr + j][col] = f2bf(gelu_f(acc[q][j] + bff1[col]));
    }
  }
  __syncthreads();
  // ---- FF2: K=512, wave w -> coltile w; y3 = acc + b + y2 in place (owner) ----
  {
    f32x4 acc = (f32x4){0.f,0.f,0.f,0.f};
    const bf16x8* B = (const bf16x8*)pFF2;
    #pragma unroll
    for (int kt = 0; kt < 16; ++kt) {
      bf16x8 a = *(const bf16x8*)&lh[l & 15][kt * 32 + (l >> 4) * 8];
      acc = __builtin_amdgcn_mfma_f32_16x16x32_bf16(a, B[(w * 16 + kt) * 64 + l], acc, 0, 0, 0);
    }
    int col = w * 16 + lc;
    #pragma unroll
    for (int j = 0; j < 4; ++j) {
      int r = lr + j;
      ly2[r][col] = acc[j] + bff2[col] + ly2[r][col];
    }
  }
  __syncthreads();
  { // ---- LN3: butterfly stats + normalize -> lnorm bf16 ----
    int r = t >> 5, j = t & 31;
    float v0 = ly2[r][j*4], v1 = ly2[r][j*4+1], v2 = ly2[r][j*4+2], v3 = ly2[r][j*4+3];
    float s1 = v0 + v1 + v2 + v3;
    float s2 = v0*v0 + v1*v1 + v2*v2 + v3*v3;
    #pragma unroll
    for (int off = 1; off < 32; off <<= 1) { s1 += __shfl_xor(s1, off); s2 += __shfl_xor(s2, off); }
    float m = s1 * (1.f / 128.f);
    float rstd = rsqrtf(s2 * (1.f / 128.f) - m * m + 1e-5f);
    float n0 = (v0 - m) * rstd * ln3s[j*4]   + ln3b[j*4];
    float n1 = (v1 - m) * rstd * ln3s[j*4+1] + ln3b[j*4+1];
    float n2 = (v2 - m) * rstd * ln3s[j*4+2] + ln3b[j*4+2];
    float n3 = (v3 - m) * rstd * ln3s[j*4+3] + ln3b[j*4+3];
    uint32_t w0 = (uint32_t)f2bf(n0) | ((uint32_t)f2bf(n1) << 16);
    uint32_t w1 = (uint32_t)f2bf(n2) | ((uint32_t)f2bf(n3) << 16);
    *(uint2*)&lnorm[r][j * 4] = (uint2){w0, w1};
  }
  __syncthreads();
  // ---- head: wave w -> coltile w; dx; masked update; x_new -> ly2 ----
  #pragma unroll
  for (int kt = 0; kt < 4; ++kt)
    a4[kt] = *(const bf16x8*)&lnorm[l & 15][kt * 32 + (l >> 4) * 8];
  {
    f32x4 acc = (f32x4){0.f,0.f,0.f,0.f};
    const bf16x8* B = (const bf16x8*)pHead;
    #pragma unroll
    for (int kt = 0; kt < 4; ++kt)
      acc = __builtin_amdgcn_mfma_f32_16x16x32_bf16(a4[kt], B[(w * 4 + kt) * 64 + l], acc, 0, 0, 0);
    int col = w * 16 + lc;
    #pragma unroll
    for (int j = 0; j < 4; ++j) {
      int r = lr + j;
      size_t n = base + r;
      float dx = acc[j] + bhead[col];
      float xn = xres[j] + dx * lmask[r];
      xout[n * 128 + col] = xn;
      ly2[r][col] = xn;
    }
  }
  // ---- tail: next step's pe + LN1 + qkv GEMM (skipped on last step) ----
  if (s + 1 < *steps) {
    __syncthreads();
    if (t < 32) { int r = t >> 1, c = 126 + (t & 1); ly2[r][c] = pe_val(base + r, c); }
    __syncthreads();
    { // LN1: butterfly stats + normalize -> lnorm bf16
      int r = t >> 5, j = t & 31;
      float v0 = ly2[r][j*4], v1 = ly2[r][j*4+1], v2 = ly2[r][j*4+2], v3 = ly2[r][j*4+3];
      float s1 = v0 + v1 + v2 + v3;
      float s2 = v0*v0 + v1*v1 + v2*v2 + v3*v3;
      #pragma unroll
      for (int off = 1; off < 32; off <<= 1) { s1 += __shfl_xor(s1, off); s2 += __shfl_xor(s2, off); }
      float m = s1 * (1.f / 128.f);
      float rstd = rsqrtf(s2 * (1.f / 128.f) - m * m + 1e-5f);
      float n0 = (v0 - m) * rstd * ln1s[j*4]   + ln1b[j*4];
      float n1 = (v1 - m) * rstd * ln1s[j*4+1] + ln1b[j*4+1];
      float n2 = (v2 - m) * rstd * ln1s[j*4+2] + ln1b[j*4+2];
      float n3 = (v3 - m) * rstd * ln1s[j*4+3] + ln1b[j*4+3];
      uint32_t w0 = (uint32_t)f2bf(n0) | ((uint32_t)f2bf(n1) << 16);
      uint32_t w1 = (uint32_t)f2bf(n2) | ((uint32_t)f2bf(n3) << 16);
      *(uint2*)&lnorm[r][j * 4] = (uint2){w0, w1};
    }
    __syncthreads();
    #pragma unroll
    for (int kt = 0; kt < 4; ++kt)
      a4[kt] = *(const bf16x8*)&lnorm[l & 15][kt * 32 + (l >> 4) * 8];
    const bf16x8* B = (const bf16x8*)pQkv;
    #pragma unroll
    for (int q = 0; q < 3; ++q) {
      f32x4 acc = (f32x4){0.f,0.f,0.f,0.f};
      int nt = w * 3 + q;
      #pragma unroll
      for (int kt = 0; kt < 4; ++kt)
        acc = __builtin_amdgcn_mfma_f32_16x16x32_bf16(a4[kt], B[(nt * 4 + kt) * 64 + l], acc, 0, 0, 0);
      int col = nt * 16 + lc;
      #pragma unroll
      for (int j = 0; j < 4; ++j)
        qkvN[(size_t)(base + lr + j) * 384 + col] = __float2half(acc[j]);
    }
  }
}

extern "C" void kernel_launch(void* const* d_in, const int* in_sizes, int n_in,
                              void* d_out, int out_size, void* d_ws, size_t ws_size,
                              hipStream_t stream) {
  const float* x0   = (const float*)d_in[0];
  const float* Wqkv = (const float*)d_in[1];
  const float* Wout = (const float*)d_in[2];
  const float* bout = (const float*)d_in[3];
  const float* ln1s = (const float*)d_in[4];
  const float* ln1b = (const float*)d_in[5];
  const float* Wff1 = (const float*)d_in[6];
  const float* bff1 = (const float*)d_in[7];
  const float* Wff2 = (const float*)d_in[8];
  const float* bff2 = (const float*)d_in[9];
  const float* ln2s = (const float*)d_in[10];
  const float* ln2b = (const float*)d_in[11];
  const float* ln3s = (const float*)d_in[12];
  const float* ln3b = (const float*)d_in[13];
  const float* Whead= (const float*)d_in[14];
  const float* bhead= (const float*)d_in[15];
  const int*   steps= (const int*)d_in[16];
  float* out = (float*)d_out;

  __half* qkvA = (__half*)d_ws;                          // N*384 f16
  __half* qkvB = qkvA + (size_t)NCELL * 384;             // N*384 f16
  unsigned short* pQkv = (unsigned short*)(qkvB + (size_t)NCELL * 384);
  unsigned short* pOut = pQkv + 128 * 384;
  unsigned short* pFF1 = pOut + 128 * 128;
  unsigned short* pFF2 = pFF1 + 128 * 512;
  unsigned short* pHead= pFF2 + 512 * 128;

  packAll<<<dim3(104), dim3(256), 0, stream>>>(Wqkv, Wout, Wff1, Wff2, Whead,
                                               pQkv, pOut, pFF1, pFF2, pHead);
  nca_k1<<<dim3(864), dim3(256), 0, stream>>>(x0, ln1s, ln1b, pQkv, qkvA, steps, 0);
  // s=0: read qkvA, write next-step qkvB; s=1: read qkvB (tail skipped)
  nca_kA<<<dim3(864), dim3(512), 0, stream>>>(qkvA, qkvB, pQkv, pOut, bout,
                                              ln1s, ln1b, ln2s, ln2b, pFF1, bff1,
                                              pFF2, bff2, ln3s, ln3b, pHead, bhead,
                                              x0, out, steps, 0);
  nca_kA<<<dim3(864), dim3(512), 0, stream>>>(qkvB, qkvA, pQkv, pOut, bout,
                                              ln1s, ln1b, ln2s, ln2b, pFF1, bff1,
                                              pFF2, bff2, ln3s, ln3b, pHead, bhead,
                                              out, out, steps, 1);
}